// Round 14
// baseline (49.037 us; speedup 1.0000x reference)
//
#include <hip/hip_runtime.h>
#include <hip/hip_fp16.h>

// OptimalTransportDepthLoss: B=65536 rows of D=256.
// loss = mean_b [ mean_i (P-Q)^2 + EMD2(P/sumP, Q/sumQ) ]
//
// EMD2 via rank formula over the stable merge of the two CDFs (validated
// rounds 3..13):
//   cp-emission at merged pos k:  coef = 2k - 4i - 1  (0 if i==255)
//   cq-emission at merged pos k:  coef = 4i - 2k - 1  (0 if j==255)
// u = 4i - 2k - 1:  coef = ea ? -(u+2) : u, u += ea ? +2 : -2. 255-elem
// zeroing fires only at merged pos 510/511 (row maxima, lane 63): single
// correction e -= |cp255 - cq255| read from LDS.
//
// Round 14: WINDOWED REGISTER MERGE. r11-13 audit: LDS pipe (~33us busy,
// 40 ops/row/lane) is the binding resource, not chain latency. The merge
// consumes exactly 8 elements from cp[i0..i0+7] / cq[j0..j0+7]; load each
// 16B window with 3 aligned ds_read_b64 + funnel shifts, then all 8 merge
// steps are pure VALU (u64 shift-register consume). LDS ops/row 40 -> 26.
// Merge decisions bit-identical (same u16-bit compares). Sentinel 0x4000 at
// [256] is never consumed -> trailing window garbage unreachable.
// Split-chain retained: corank(r+1) LDS chain interleaves with merge(r)
// VALU. f16 LDS staging, double-buffered wave-private LDS, no lgkmcnt asm
// (per-wave DS in-order), register prefetch, f64 accumulation, (256,8).

#define NW    4      // waves per block
#define DSZ   256    // histogram length
#define LROW  272    // halves: 256 vals + sentinel@256 + window pad; 8B-aligned rows

template <int CTRL, int RMASK, bool BC>
__device__ __forceinline__ float dpp_add(float x) {
    int t = __builtin_amdgcn_update_dpp(0, __float_as_int(x), CTRL, RMASK, 0xf, BC);
    return x + __int_as_float(t);
}

// wave64 inclusive scan
__device__ __forceinline__ float wave_scan(float x) {
    x = dpp_add<0x111, 0xf, true >(x);   // row_shr:1
    x = dpp_add<0x112, 0xf, true >(x);   // row_shr:2
    x = dpp_add<0x114, 0xf, true >(x);   // row_shr:4
    x = dpp_add<0x118, 0xf, true >(x);   // row_shr:8
    x = dpp_add<0x142, 0xa, false>(x);   // row_bcast:15 -> rows 1,3
    x = dpp_add<0x143, 0xc, false>(x);   // row_bcast:31 -> rows 2,3
    return x;
}

__device__ __forceinline__ float lane63(float x) {
    return __int_as_float(__builtin_amdgcn_readlane(__float_as_int(x), 63));
}

__device__ __forceinline__ unsigned short f2h(float x) {
    return __half_as_ushort(__float2half(x));     // v_cvt_f16_f32 (RTN)
}
__device__ __forceinline__ float h2f(unsigned int x) {
    return __half2float(__ushort_as_half((unsigned short)x)); // v_cvt_f32_f16
}

// front-end one row: MSE partial + normalized CDF staged to LDS as f16
__device__ __forceinline__ float fe_stage(const float4 pv, const float4 qv,
                                          unsigned short* cp, unsigned short* cq,
                                          int lane) {
    float dx = pv.x - qv.x, dy = pv.y - qv.y;
    float dz = pv.z - qv.z, dw = pv.w - qv.w;
    float msel = dx*dx + dy*dy + dz*dz + dw*dw;

    float pl = pv.x + pv.y + pv.z + pv.w;
    float ql = qv.x + qv.y + qv.z + qv.w;
    float ps = wave_scan(pl);
    float qs = wave_scan(ql);
    float rp = __builtin_amdgcn_rcpf(lane63(ps));
    float rq = __builtin_amdgcn_rcpf(lane63(qs));
    float pe = ps - pl, qe = qs - ql;

    ushort4 hP = make_ushort4(f2h((pe + pv.x) * rp),
                              f2h((pe + pv.x + pv.y) * rp),
                              f2h((pe + pv.x + pv.y + pv.z) * rp),
                              f2h(ps * rp));
    ushort4 hQ = make_ushort4(f2h((qe + qv.x) * rq),
                              f2h((qe + qv.x + qv.y) * rq),
                              f2h((qe + qv.x + qv.y + qv.z) * rq),
                              f2h(qs * rq));
    *reinterpret_cast<ushort4*>(&cp[lane * 4]) = hP;   // 8B ds_write_b64
    *reinterpret_cast<ushort4*>(&cq[lane * 4]) = hQ;
    return msel;
}

// corank(row r+1) interleaved with register-window merge(row r).
// Returns EMD partial of row r; writes corank of row r+1 to loN.
__device__ __forceinline__ float corank_merge(
    const unsigned short* cpN, const unsigned short* cqN,  // next row (search)
    const unsigned short* cpC, const unsigned short* cqC,  // cur row (merge)
    int k0, int loC, bool is63, int& loN)
{
    // ---- merge windows: cp[i0..i0+7], cq[j0..j0+7] via 3 aligned b64/side
    const int i0 = loC;
    const int j0 = k0 - loC;
    const unsigned long long* A64 = reinterpret_cast<const unsigned long long*>(cpC);
    const unsigned long long* B64 = reinterpret_cast<const unsigned long long*>(cqC);
    const int qa = i0 >> 2, qb = j0 >> 2;
    unsigned long long A0 = A64[qa], A1 = A64[qa + 1], A2 = A64[qa + 2];
    unsigned long long B0 = B64[qb], B1 = B64[qb + 1], B2 = B64[qb + 2];
    const int sa = (i0 & 3) << 4;     // bit shift 0/16/32/48
    const int sb = (j0 & 3) << 4;
    unsigned long long aLo = sa ? ((A0 >> sa) | (A1 << (64 - sa))) : A0;
    unsigned long long aHi = sa ? ((A1 >> sa) | (A2 << (64 - sa))) : A1;
    unsigned long long bLo = sb ? ((B0 >> sb) | (B1 << (64 - sb))) : B0;
    unsigned long long bHi = sb ? ((B1 >> sb) | (B2 << (64 - sb))) : B1;

    // corank state (row r+1)
    int lo = k0 > DSZ ? k0 - DSZ : 0;
    int hi = k0 < DSZ ? k0 : DSZ;

    float u  = (float)(4 * loC - 2 * k0 - 1);
    float e_ = 0.0f;
#pragma unroll
    for (int s = 0; s < 9; ++s) {
        {   // corank step s (the only LDS chain this iteration)
            int mid = (lo + hi) >> 1;
            int jm  = k0 - 1 - mid;
            int jr  = jm < 0 ? 0 : jm;
            unsigned int qq = cqN[jr];
            unsigned int cc = cpN[mid];
            bool pred = (jm < 0) || (qq <= cc);
            hi = pred ? mid : hi;
            lo = pred ? lo  : mid + 1;
        }
        if (s < 8) {   // merge step s — pure VALU on register windows
            unsigned int aH = (unsigned int)aLo & 0xFFFFu;
            unsigned int bH = (unsigned int)bLo & 0xFFFFu;
            bool  ea   = aH < bH;           // emit cp only if strictly smaller
            float val  = h2f(ea ? aH : bH);
            float u2   = u + 2.0f;
            float coef = ea ? -u2 : u;
            e_ = fmaf(val, coef, e_);
            u  = ea ? u2 : (u - 2.0f);
            unsigned long long nAlo = (aLo >> 16) | (aHi << 48);
            unsigned long long nAhi = aHi >> 16;
            unsigned long long nBlo = (bLo >> 16) | (bHi << 48);
            unsigned long long nBhi = bHi >> 16;
            aLo = ea ? nAlo : aLo;  aHi = ea ? nAhi : aHi;
            bLo = ea ? bLo : nBlo;  bHi = ea ? bHi : nBhi;
        }
    }
    loN = lo;
    // lane-63 correction: merged pos 510/511 hold the row maxima with true
    // coef 0; uncorrected sum is +/-(cp255-cq255).
    e_ -= is63 ? fabsf(h2f(cpC[DSZ - 1]) - h2f(cqC[DSZ - 1])) : 0.0f;
    return e_;
}

__global__ __launch_bounds__(256, 8) void otdl_main(
    const float* __restrict__ P, const float* __restrict__ Q,
    double* __restrict__ partial, int B, int bpw)
{
    __shared__ unsigned short s_cp[NW][2][LROW];   // [wave][buf][...]
    __shared__ unsigned short s_cq[NW][2][LROW];
    __shared__ double s_bsum[NW];

    const int tid  = threadIdx.x;
    const int wv   = tid >> 6;
    const int lane = tid & 63;
    const int wgl  = blockIdx.x * NW + wv;   // global wave id

    // sentinel = f16 2.0 (0x4000) > all CDF values; wave-private, ordered by
    // the in-order DS pipe before any later read.
    if (lane == 0) {
        s_cp[wv][0][DSZ] = 0x4000; s_cq[wv][0][DSZ] = 0x4000;
        s_cp[wv][1][DSZ] = 0x4000; s_cq[wv][1][DSZ] = 0x4000;
    }

    double acc = 0.0;
    const int  k0      = lane * 8;           // this lane's merge diagonal
    const long rowbase = (long)wgl * bpw;
    const bool is63    = (lane == 63);

    // load row 0
    float4 pv, qv;
    {
        long c = (rowbase < B) ? rowbase : (B - 1);
        pv = reinterpret_cast<const float4*>(P + c * DSZ)[lane];
        qv = reinterpret_cast<const float4*>(Q + c * DSZ)[lane];
    }

    // prologue: FE+stage row 0 -> buf0, corank(row 0), then load row 1
    float mselC = fe_stage(pv, qv, s_cp[wv][0], s_cq[wv][0], lane);
    if (bpw > 1) {
        long c = (rowbase + 1 < B) ? rowbase + 1 : (B - 1);
        pv = reinterpret_cast<const float4*>(P + c * DSZ)[lane];
        qv = reinterpret_cast<const float4*>(Q + c * DSZ)[lane];
    }
    int loC;
    {   // standalone corank of row 0 (prologue only)
        const unsigned short* cp = s_cp[wv][0];
        const unsigned short* cq = s_cq[wv][0];
        int lo = k0 > DSZ ? k0 - DSZ : 0;
        int hi = k0 < DSZ ? k0 : DSZ;
#pragma unroll
        for (int s = 0; s < 9; ++s) {
            int mid = (lo + hi) >> 1;
            int jm  = k0 - 1 - mid;
            int jr  = jm < 0 ? 0 : jm;
            unsigned int qq = cq[jr];
            unsigned int cc = cp[mid];
            bool pred = (jm < 0) || (qq <= cc);
            hi = pred ? mid : hi;
            lo = pred ? lo  : mid + 1;
        }
        loC = lo;
    }

#pragma unroll 2
    for (int r = 0; r < bpw; ++r) {
        const int cur = r & 1;
        unsigned short* cpN = s_cp[wv][cur ^ 1];
        unsigned short* cqN = s_cq[wv][cur ^ 1];
        const unsigned short* cpC = s_cp[wv][cur];
        const unsigned short* cqC = s_cq[wv][cur];

        // ---- FE+stage row r+1 (pure VALU + 2 ds_write) ----
        float mselN = 0.0f;
        if (r + 1 < bpw) {
            mselN = fe_stage(pv, qv, cpN, cqN, lane);
        }
        // ---- issue global loads for row r+2 ----
        if (r + 2 < bpw) {
            long c = (rowbase + r + 2 < B) ? rowbase + r + 2 : (B - 1);
            pv = reinterpret_cast<const float4*>(P + c * DSZ)[lane];
            qv = reinterpret_cast<const float4*>(Q + c * DSZ)[lane];
        }

        // ---- corank(r+1) || register-window merge(r) ----
        // (corank reads cpN even when r+1>=bpw: stale data, result unused)
        int loN;
        float e_ = corank_merge(cpN, cqN, cpC, cqC, k0, loC, is63, loN);

        if (rowbase + r < B) acc += (double)(e_ + mselC * (1.0f / 256.0f));
        mselC = mselN;
        loC   = loN;
    }

    // ---- wave reduce (f64), then block reduce ----
#pragma unroll
    for (int off = 32; off; off >>= 1) {
        double o = __shfl_xor(acc, off, 64);
        acc += o;
    }
    if (lane == 0) s_bsum[wv] = acc;
    __syncthreads();
    if (tid == 0) {
        partial[blockIdx.x] = s_bsum[0] + s_bsum[1] + s_bsum[2] + s_bsum[3];
    }
}

__global__ __launch_bounds__(256) void otdl_reduce(
    const double* __restrict__ partial, int n, float* __restrict__ out, double invB)
{
    __shared__ double sdata[256];
    double a = 0.0;
    for (int i = threadIdx.x; i < n; i += 256) a += partial[i];
    sdata[threadIdx.x] = a;
    __syncthreads();
    for (int s2 = 128; s2 > 0; s2 >>= 1) {
        if (threadIdx.x < s2) sdata[threadIdx.x] += sdata[threadIdx.x + s2];
        __syncthreads();
    }
    if (threadIdx.x == 0) out[0] = (float)(sdata[0] * invB);
}

extern "C" void kernel_launch(void* const* d_in, const int* in_sizes, int n_in,
                              void* d_out, int out_size, void* d_ws, size_t ws_size,
                              hipStream_t stream)
{
    const float* P = (const float*)d_in[0];
    const float* Q = (const float*)d_in[1];
    float* out = (float*)d_out;
    double* partial = (double*)d_ws;

    int B = in_sizes[0] / DSZ;          // 65536
    const int blocks = 2048;
    const int totalWaves = blocks * NW; // 8192
    int bpw = (B + totalWaves - 1) / totalWaves;  // 8

    otdl_main<<<blocks, 256, 0, stream>>>(P, Q, partial, B, bpw);
    otdl_reduce<<<1, 256, 0, stream>>>(partial, blocks, out, 1.0 / (double)B);
}

// Round 15
// 38.967 us; speedup vs baseline: 1.2584x; 1.2584x over previous
//
#include <hip/hip_runtime.h>
#include <hip/hip_fp16.h>

// OptimalTransportDepthLoss: B=65536 rows of D=256.
// loss = mean_b [ mean_i (P-Q)^2 + EMD2(P/sumP, Q/sumQ) ]
//
// EMD2 via rank formula over the stable merge of the two CDFs (validated
// rounds 3..13):
//   cp-emission at merged pos k:  coef = 2k - 4i - 1  (0 if i==255)
//   cq-emission at merged pos k:  coef = 4i - 2k - 1  (0 if j==255)
// u = 4i - 2k - 1:  coef = ea ? -(u+2) : u, u += ea ? +2 : -2. 255-elem
// zeroing fires only at merged pos 510/511 (row maxima): single correction
// e -= |cp255 - cq255| at the last lane of each half.
//
// Round 15: HALF-WAVE ROW SPLIT. rounds 11-14 showed the binding constraint
// is per-row wave-instruction count + serial depth (no pipe saturated).
// Lanes 0-31 own row 2p, lanes 32-63 own row 2p+1 (8 elems/lane): every
// wave instruction now serves TWO rows. Scan = 5-step DPP (32-lane halves);
// corank k0=(lane&31)*16 (18 LDS reads serve 2 rows); merge 16 steps/lane;
// staging one b128/array/pair. Per-row: VALU ~240->180, LDS ~40->30,
// depth -26%. Keeps validated f16 staging, r11 pipeline (FE+stage(p+1) ||
// corank+merge(p), no waits - per-wave DS in-order, distance = full iter),
// register prefetch, f64 accumulation. (256,6): natural VGPR ~55-60, the
// 64-cap of (256,8) would spill (r8/r9 lesson; WRITE_SIZE tripwire).

#define NW    4      // waves per block
#define DSZ   256    // histogram length
#define LROW  264    // u16: 256 vals + sentinel@256 + readahead pad; 8B-aligned

template <int CTRL, int RMASK, bool BC>
__device__ __forceinline__ float dpp_add(float x) {
    int t = __builtin_amdgcn_update_dpp(0, __float_as_int(x), CTRL, RMASK, 0xf, BC);
    return x + __int_as_float(t);
}

// 32-lane inclusive scan within each wave half (first 5 steps of the wave64
// scan; row_bcast:31 omitted so halves stay independent)
__device__ __forceinline__ float half_scan(float x) {
    x = dpp_add<0x111, 0xf, true >(x);   // row_shr:1
    x = dpp_add<0x112, 0xf, true >(x);   // row_shr:2
    x = dpp_add<0x114, 0xf, true >(x);   // row_shr:4
    x = dpp_add<0x118, 0xf, true >(x);   // row_shr:8
    x = dpp_add<0x142, 0xa, false>(x);   // row_bcast:15 -> rows 1,3
    return x;
}

__device__ __forceinline__ float rdlane31(float x) {
    return __int_as_float(__builtin_amdgcn_readlane(__float_as_int(x), 31));
}
__device__ __forceinline__ float rdlane63(float x) {
    return __int_as_float(__builtin_amdgcn_readlane(__float_as_int(x), 63));
}

__device__ __forceinline__ unsigned int f2h(float x) {
    return (unsigned int)__half_as_ushort(__float2half(x));  // RTN
}
__device__ __forceinline__ float h2f(unsigned int x) {
    return __half2float(__ushort_as_half((unsigned short)x));
}

// front-end: each lane handles 8 elems of its half's row; stages f16 CDF
// (one b128 per array); returns the lane's MSE partial.
__device__ __forceinline__ float fe_stage(
    const float4 pA, const float4 pB, const float4 qA, const float4 qB,
    unsigned short* cp, unsigned short* cq, int l32, bool hiHalf)
{
    float d0 = pA.x - qA.x, d1 = pA.y - qA.y, d2 = pA.z - qA.z, d3 = pA.w - qA.w;
    float d4 = pB.x - qB.x, d5 = pB.y - qB.y, d6 = pB.z - qB.z, d7 = pB.w - qB.w;
    float msel = d0*d0 + d1*d1 + d2*d2 + d3*d3 + d4*d4 + d5*d5 + d6*d6 + d7*d7;

    float pl = (pA.x + pA.y + pA.z + pA.w) + (pB.x + pB.y + pB.z + pB.w);
    float ql = (qA.x + qA.y + qA.z + qA.w) + (qB.x + qB.y + qB.z + qB.w);
    float ps = half_scan(pl);
    float qs = half_scan(ql);

    float ptot = hiHalf ? rdlane63(ps) : rdlane31(ps);
    float qtot = hiHalf ? rdlane63(qs) : rdlane31(qs);
    float rp = __builtin_amdgcn_rcpf(ptot);
    float rq = __builtin_amdgcn_rcpf(qtot);
    float pe = ps - pl, qe = qs - ql;

    // in-lane cumsums (8 per array); last = inclusive scan value
    float p0 = pe + pA.x, p1 = p0 + pA.y, p2 = p1 + pA.z, p3 = p2 + pA.w;
    float p4 = p3 + pB.x, p5 = p4 + pB.y, p6 = p5 + pB.z;
    float q0 = qe + qA.x, q1 = q0 + qA.y, q2 = q1 + qA.z, q3 = q2 + qA.w;
    float q4 = q3 + qB.x, q5 = q4 + qB.y, q6 = q5 + qB.z;

    uint4 wp, wq;
    wp.x = f2h(p0 * rp) | (f2h(p1 * rp) << 16);
    wp.y = f2h(p2 * rp) | (f2h(p3 * rp) << 16);
    wp.z = f2h(p4 * rp) | (f2h(p5 * rp) << 16);
    wp.w = f2h(p6 * rp) | (f2h(ps * rp) << 16);
    wq.x = f2h(q0 * rq) | (f2h(q1 * rq) << 16);
    wq.y = f2h(q2 * rq) | (f2h(q3 * rq) << 16);
    wq.z = f2h(q4 * rq) | (f2h(q5 * rq) << 16);
    wq.w = f2h(q6 * rq) | (f2h(qs * rq) << 16);

    *reinterpret_cast<uint4*>(&cp[l32 * 8]) = wp;   // one ds_write_b128
    *reinterpret_cast<uint4*>(&cq[l32 * 8]) = wq;
    return msel;
}

__global__ __launch_bounds__(256, 6) void otdl_main(
    const float* __restrict__ P, const float* __restrict__ Q,
    double* __restrict__ partial, int B, int bpw)
{
    __shared__ unsigned short s_cp[NW][2][2][LROW];   // [wave][buf][rowhalf][...]
    __shared__ unsigned short s_cq[NW][2][2][LROW];
    __shared__ double s_bsum[NW];

    const int tid  = threadIdx.x;
    const int wv   = tid >> 6;
    const int lane = tid & 63;
    const int l32  = lane & 31;
    const bool hiHalf = (lane >= 32);
    const int rh   = hiHalf ? 1 : 0;
    const int wgl  = blockIdx.x * NW + wv;   // global wave id

    // f16 sentinel 2.0 (0x4000) > all CDF values; wave-private, ordered by
    // the in-order DS pipe before any later read.
    if (lane == 0) {
#pragma unroll
        for (int bf = 0; bf < 2; ++bf)
#pragma unroll
            for (int r2 = 0; r2 < 2; ++r2) {
                s_cp[wv][bf][r2][DSZ] = 0x4000;
                s_cq[wv][bf][r2][DSZ] = 0x4000;
            }
    }

    double acc = 0.0;
    const int  k0      = l32 * 16;           // this lane's merge diagonal
    const int  npair   = (bpw + 1) >> 1;
    const long rowbase = (long)wgl * bpw;
    const bool isLast  = (l32 == 31);

    // load pair 0 (each lane: its half's row, 8 elems)
    float4 pA, pB, qA, qB;
    {
        long b = rowbase + rh;
        long c = (b < B) ? b : (B - 1);
        const float4* Pr = reinterpret_cast<const float4*>(P + c * DSZ + l32 * 8);
        const float4* Qr = reinterpret_cast<const float4*>(Q + c * DSZ + l32 * 8);
        pA = Pr[0]; pB = Pr[1];
        qA = Qr[0]; qB = Qr[1];
    }

    // prologue: FE+stage pair 0 -> buf0, then load pair 1
    float mselC = fe_stage(pA, pB, qA, qB, s_cp[wv][0][rh], s_cq[wv][0][rh],
                           l32, hiHalf);
    if (npair > 1) {
        long b = rowbase + 2 + rh;
        long c = (b < B) ? b : (B - 1);
        const float4* Pr = reinterpret_cast<const float4*>(P + c * DSZ + l32 * 8);
        const float4* Qr = reinterpret_cast<const float4*>(Q + c * DSZ + l32 * 8);
        pA = Pr[0]; pB = Pr[1];
        qA = Qr[0]; qB = Qr[1];
    }

#pragma unroll 2
    for (int p = 0; p < npair; ++p) {
        const int cur = p & 1;

        // ---- FE+stage pair p+1 into the other buffer ----
        float mselN = 0.0f;
        if (p + 1 < npair) {
            mselN = fe_stage(pA, pB, qA, qB,
                             s_cp[wv][cur ^ 1][rh], s_cq[wv][cur ^ 1][rh],
                             l32, hiHalf);
        }
        // ---- issue global loads for pair p+2 ----
        if (p + 2 < npair) {
            long b = rowbase + 2 * (p + 2) + rh;
            long c = (b < B) ? b : (B - 1);
            const float4* Pr = reinterpret_cast<const float4*>(P + c * DSZ + l32 * 8);
            const float4* Qr = reinterpret_cast<const float4*>(Q + c * DSZ + l32 * 8);
            pA = Pr[0]; pB = Pr[1];
            qA = Qr[0]; qB = Qr[1];
        }

        const unsigned short* cp = s_cp[wv][cur][rh];
        const unsigned short* cq = s_cq[wv][cur][rh];

        // ---- binary co-rank: smallest i in [lo,hi] with cq[k0-1-i] <= cp[i]
        //      (u16-bit compares: positive f16 monotone in bit pattern)
        int lo = k0 > DSZ ? k0 - DSZ : 0;
        int hi = k0 < DSZ ? k0 : DSZ;
#pragma unroll
        for (int s = 0; s < 9; ++s) {
            int mid = (lo + hi) >> 1;
            int jm  = k0 - 1 - mid;
            int jr  = jm < 0 ? 0 : jm;
            unsigned int qq = cq[jr];
            unsigned int cc = cp[mid];
            bool pred = (jm < 0) || (qq <= cc);
            hi = pred ? mid : hi;
            lo = pred ? lo  : mid + 1;
        }

        // ---- 16 merge steps (this lane's merged positions k0..k0+15) ----
        const unsigned short* pA_ = cp + lo;
        const unsigned short* pB_ = cq + (k0 - lo);
        float u  = (float)(4 * lo - 2 * k0 - 1);
        unsigned int a  = pA_[0];
        unsigned int b2 = pB_[0];
        unsigned int an = pA_[1];
        unsigned int bn = pB_[1];
        float e_ = 0.0f;
#pragma unroll
        for (int s = 0; s < 16; ++s) {
            bool  ea   = a < b2;
            float val  = h2f(ea ? a : b2);
            float u2   = u + 2.0f;
            float coef = ea ? -u2 : u;
            e_ = fmaf(val, coef, e_);
            u  = ea ? u2 : (u - 2.0f);
            pA_ += ea ? 1 : 0;
            pB_ += ea ? 0 : 1;
            a  = ea ? an : a;
            b2 = ea ? b2 : bn;
            an = pA_[1];
            bn = pB_[1];
        }

        // last-lane correction: merged pos 510/511 hold the row maxima with
        // true coef 0; uncorrected sum is +/-(cp255-cq255).
        e_ -= isLast ? fabsf(h2f(cp[DSZ - 1]) - h2f(cq[DSZ - 1])) : 0.0f;

        if (rowbase + 2 * p + rh < B)
            acc += (double)(e_ + mselC * (1.0f / 256.0f));
        mselC = mselN;
    }

    // ---- wave reduce (f64) sums both halves' rows, then block reduce ----
#pragma unroll
    for (int off = 32; off; off >>= 1) {
        double o = __shfl_xor(acc, off, 64);
        acc += o;
    }
    if (lane == 0) s_bsum[wv] = acc;
    __syncthreads();
    if (tid == 0) {
        partial[blockIdx.x] = s_bsum[0] + s_bsum[1] + s_bsum[2] + s_bsum[3];
    }
}

__global__ __launch_bounds__(256) void otdl_reduce(
    const double* __restrict__ partial, int n, float* __restrict__ out, double invB)
{
    __shared__ double sdata[256];
    double a = 0.0;
    for (int i = threadIdx.x; i < n; i += 256) a += partial[i];
    sdata[threadIdx.x] = a;
    __syncthreads();
    for (int s2 = 128; s2 > 0; s2 >>= 1) {
        if (threadIdx.x < s2) sdata[threadIdx.x] += sdata[threadIdx.x + s2];
        __syncthreads();
    }
    if (threadIdx.x == 0) out[0] = (float)(sdata[0] * invB);
}

extern "C" void kernel_launch(void* const* d_in, const int* in_sizes, int n_in,
                              void* d_out, int out_size, void* d_ws, size_t ws_size,
                              hipStream_t stream)
{
    const float* P = (const float*)d_in[0];
    const float* Q = (const float*)d_in[1];
    float* out = (float*)d_out;
    double* partial = (double*)d_ws;

    int B = in_sizes[0] / DSZ;          // 65536
    const int blocks = 2048;
    const int totalWaves = blocks * NW; // 8192
    int bpw = (B + totalWaves - 1) / totalWaves;  // 8

    otdl_main<<<blocks, 256, 0, stream>>>(P, Q, partial, B, bpw);
    otdl_reduce<<<1, 256, 0, stream>>>(partial, blocks, out, 1.0 / (double)B);
}